// Round 13
// baseline (109.862 us; speedup 1.0000x reference)
//
#include <hip/hip_runtime.h>

#define NBINS 2304                 // rebased: bin = (float_bits(d)>>18) - BINBASE
#define BINBASE 2048               // bin 0 <-> d ~ 5.4e-19; d<=4 -> bin <= 2113
#define ACC_OFF (3 * NBINS)        // ws_f word offset: per-layer n^2 sums [3]
#define CTR_OFF (ACC_OFF + 4)      // ws_u word offset: work-stealing tile counter
#define NTILES 1792                // 256 (layer2) + 512 (layer1) + 1024 (layer0)

typedef float    f4v __attribute__((ext_vector_type(4)));
typedef _Float16 h4v __attribute__((ext_vector_type(4)));

// ---- r11 tile body (measured best). Tile = 16K elements (P positions x C
// channels) of one batch image; every thread 16 channels x 4 consecutive
// positions; t,s,n loaded together (12 float4 in flight per thread); t,s
// retained as f16; f32 norms reduce through LDS; register-only d histogram.
//
// Hard-won constraints (do not violate):
//  - DO NOT restructure the load loop (r5/r6: pipelines collapsed MLP/spilled).
//  - DO NOT split n into separate streaming blocks (r5, r12: regression —
//    fused 12-deep load loop beats grid-level phase mixing).
//  - DO NOT fuse finalize behind a ticket (r7: acq_rel = +140us cache-maint).
//  - launch_bounds waves-arg >= 4 flips the compiler into pressure-limited
//    scheduling and spills th/sh (r3/r5/r9/r10). KEEP (256,3); VGPR must stay
//    ~84-96 with zero scratch traffic.
template<int C, int HWSHIFT, int PSHIFT, int LAYER>
__device__ __forceinline__ void hist_layer(
    const float* __restrict__ t, const float* __restrict__ s, const float* __restrict__ n,
    int lb, unsigned int* __restrict__ ws_u, float* __restrict__ ws_f,
    unsigned int* cnt_sh, float* ov_sh, float* inv_sh)
{
    const int HW  = 1 << HWSHIFT;
    const int P   = 1 << PSHIFT;        // positions per tile: 256/128/64
    const int NPQ = P >> 2;             // position-quads per wave: 64/32/16
    const int G   = 1024 >> PSHIFT;     // norm partials per position: 4/8/16
    const int tid = threadIdx.x;
    const int w   = tid >> 6;
    const int l   = tid & 63;
    const int pq  = l & (NPQ - 1);      // which position-quad
    const int cs  = l >> (PSHIFT - 2);  // channel sub-group within wave

    const int p0 = lb << PSHIFT;        // first flat position (never straddles b)
    const int b  = p0 >> HWSHIFT;
    const int q  = p0 & (HW - 1);
    const int c0 = w * (C / 4) + cs * 16;
    const size_t base = ((size_t)(b * C + c0) << HWSHIFT) + q + 4 * pq;

    const float* tp = t + base;
    const float* sp = s + base;
    const float* np = n + base;

    // ---- zero histogram up-front: hides under the in-flight global loads;
    //      WAR vs previous tile's flush is guarded by the caller's barrier ----
    #pragma unroll
    for (int i = tid; i < NBINS / 4; i += 256)
        ((uint4*)cnt_sh)[i] = make_uint4(0u, 0u, 0u, 0u);

    // ---- pass 1: batched loads (12 float4 in flight), f32 norm accum, f16 retain ----
    h4v th[16], sh[16];
    f4v accT = {0.f,0.f,0.f,0.f}, accS = {0.f,0.f,0.f,0.f};
    float aN = 0.f;

    #pragma unroll
    for (int k0 = 0; k0 < 16; k0 += 4) {
        f4v tt[4], ss[4], nn[4];
        #pragma unroll
        for (int u = 0; u < 4; ++u) {
            const size_t o = (size_t)(k0 + u) << HWSHIFT;
            tt[u] = *(const f4v*)(tp + o);
            ss[u] = *(const f4v*)(sp + o);
            nn[u] = __builtin_nontemporal_load((const f4v*)(np + o));
        }
        #pragma unroll
        for (int u = 0; u < 4; ++u) {
            accT += tt[u] * tt[u];
            accS += ss[u] * ss[u];
            aN += nn[u].x*nn[u].x + nn[u].y*nn[u].y + nn[u].z*nn[u].z + nn[u].w*nn[u].w;
            th[k0+u] = (h4v){(_Float16)tt[u].x, (_Float16)tt[u].y,
                             (_Float16)tt[u].z, (_Float16)tt[u].w};
            sh[k0+u] = (h4v){(_Float16)ss[u].x, (_Float16)ss[u].y,
                             (_Float16)ss[u].z, (_Float16)ss[u].w};
        }
    }

    // cross-wave/lane-group norm combine via dedicated ov_sh buffer
    float* ovT = ov_sh;                 // [G][P] = 1024 floats
    float* ovS = ov_sh + 1024;          // 1024 floats
    float* ovN = ov_sh + 2048;          // 4 floats
    const int g = (w * (64 / NPQ)) + cs;        // partial group id, 0..G-1
    ((f4v*)ovT)[g * NPQ + pq] = accT;           // linearizes to ovT[g*P + pos]
    ((f4v*)ovS)[g * NPQ + pq] = accS;
    #pragma unroll
    for (int o = 32; o > 0; o >>= 1) aN += __shfl_down(aN, o, 64);
    if (l == 0) ovN[w] = aN;
    __syncthreads();

    if (tid < P) {
        float nT = 0.f, nS = 0.f;
        #pragma unroll
        for (int gg = 0; gg < G; ++gg) { nT += ovT[gg * P + tid]; nS += ovS[gg * P + tid]; }
        inv_sh[tid]     = 1.0f / fmaxf(sqrtf(nT), 1e-12f);
        inv_sh[P + tid] = 1.0f / fmaxf(sqrtf(nS), 1e-12f);
    }
    if (tid == 0)
        atomicAdd(&ws_f[ACC_OFF + LAYER], ovN[0] + ovN[1] + ovN[2] + ovN[3]);
    __syncthreads();

    // ---- pass 2 (registers only): d = (t*invT - s*invS)^2, count histogram ----
    __builtin_amdgcn_s_setprio(1);      // r8: neutral-to-slightly-positive, keep
    f4v iT = ((const f4v*)inv_sh)[pq];
    f4v iS = ((const f4v*)(inv_sh + P))[pq];
    #pragma unroll
    for (int k = 0; k < 16; ++k) {
        f4v tv = {(float)th[k].x, (float)th[k].y, (float)th[k].z, (float)th[k].w};
        f4v sv = {(float)sh[k].x, (float)sh[k].y, (float)sh[k].z, (float)sh[k].w};
        f4v a  = tv * iT - sv * iS;
        f4v d  = a * a;
        int b0 = min(max((int)(__float_as_uint(d.x) >> 18) - BINBASE, 0), NBINS - 1);
        int b1 = min(max((int)(__float_as_uint(d.y) >> 18) - BINBASE, 0), NBINS - 1);
        int b2 = min(max((int)(__float_as_uint(d.z) >> 18) - BINBASE, 0), NBINS - 1);
        int b3 = min(max((int)(__float_as_uint(d.w) >> 18) - BINBASE, 0), NBINS - 1);
        atomicAdd(&cnt_sh[b0], 1u);
        atomicAdd(&cnt_sh[b1], 1u);
        atomicAdd(&cnt_sh[b2], 1u);
        atomicAdd(&cnt_sh[b3], 1u);
    }
    __syncthreads();

    // ---- flush nonzero bins to global per-layer histogram ----
    unsigned int* gc = ws_u + LAYER * NBINS;
    #pragma unroll
    for (int i = tid; i < NBINS; i += 256) {
        unsigned c = cnt_sh[i];
        if (c) atomicAdd(&gc[i], c);
    }
    __builtin_amdgcn_s_setprio(0);
}

// Persistent blocks + dynamic work stealing: 768 blocks (3/CU residency),
// each steals tiles via a global counter until all NTILES are consumed.
// Kills per-block launch/drain overhead and the static-schedule tail.
__global__ __launch_bounds__(256, 3) void stfpm_hist(
    const float* __restrict__ t0, const float* __restrict__ s0, const float* __restrict__ n0,
    const float* __restrict__ t1, const float* __restrict__ s1, const float* __restrict__ n1,
    const float* __restrict__ t2, const float* __restrict__ s2, const float* __restrict__ n2,
    unsigned int* __restrict__ ws_u, float* __restrict__ ws_f)
{
    __shared__ __align__(16) unsigned int cnt_sh[NBINS];  // 9.2 KB
    __shared__ __align__(16) float ov_sh[2052];           // 8.2 KB norm overlay
    __shared__ __align__(16) float inv_sh[512];           // 2 KB
    __shared__ int tile_sh;

    for (;;) {
        if (threadIdx.x == 0)
            tile_sh = (int)atomicAdd(&ws_u[CTR_OFF], 1u);
        __syncthreads();            // broadcast tile; also WAR-guards cnt_sh reuse
        const int tile = tile_sh;
        if (tile >= NTILES) break;

        if (tile < 256)
            hist_layer<256, 10, 6, 2>(t2, s2, n2, tile,       ws_u, ws_f, cnt_sh, ov_sh, inv_sh);
        else if (tile < 768)
            hist_layer<128, 12, 7, 1>(t1, s1, n1, tile - 256, ws_u, ws_f, cnt_sh, ov_sh, inv_sh);
        else
            hist_layer<64,  14, 8, 0>(t0, s0, n0, tile - 768, ws_u, ws_f, cnt_sh, ov_sh, inv_sh);
    }
}

__device__ __forceinline__ float bin_lo(int b) {
    return __uint_as_float((unsigned)(b + BINBASE) << 18);
}
__device__ __forceinline__ float bin_mid(int b) {
    return 0.5f * (bin_lo(b) + bin_lo(b + 1));
}

// Single block: per layer, scan counts from the top; full bins above the
// boundary contribute cnt * bin-midpoint; boundary bin uses the uniform-
// within-bin model for its top-j elements. Adds mean(n^2); writes the scalar.
__global__ __launch_bounds__(256) void stfpm_finalize(
    const unsigned int* __restrict__ ws_u, const float* __restrict__ ws_f,
    float* __restrict__ out)
{
    __shared__ unsigned int cchunk[256];
    __shared__ float        schunk[256];
    const int tid = threadIdx.x;

    const int   targets[3] = {16778, 8389, 4195};  // cnt = N-1-floor(0.999(N-1))
    const float Ns[3]      = {16777216.f, 8388608.f, 4194304.f};
    const int   CHUNK = NBINS / 256;  // 9

    float total = 0.f;  // thread 0 only
    for (int layer = 0; layer < 3; ++layer) {
        const unsigned int* gc = ws_u + layer * NBINS;
        unsigned int c = 0; float sv = 0.f;
        const int b0 = tid * CHUNK;
        for (int i = 0; i < CHUNK; ++i) {
            unsigned cc = gc[b0 + i];
            c += cc;
            if (cc) sv += (float)cc * bin_mid(b0 + i);
        }
        __syncthreads();
        cchunk[tid] = c; schunk[tid] = sv;
        __syncthreads();
        if (tid == 0) {
            const int target = targets[layer];
            long long cum = 0; float sAbove = 0.f;
            int ch = 255;
            while (ch >= 0 && cum + (long long)cchunk[ch] < target) {
                cum += cchunk[ch]; sAbove += schunk[ch]; --ch;
            }
            int bin = ch * CHUNK + CHUNK - 1;
            while (bin >= ch * CHUNK && cum + (long long)gc[bin] < target) {
                unsigned cc = gc[bin];
                cum += cc; sAbove += (float)cc * bin_mid(bin); --bin;
            }
            unsigned cb = gc[bin];          // boundary bin count (>=1)
            int j = target - (int)cum;      // elements taken from boundary bin
            float lo = bin_lo(bin), hi = bin_lo(bin + 1);
            float wd = hi - lo;
            float f  = (float)j / (float)cb;
            float topmean = hi - f * wd * 0.5f;  // mean of top-j under uniform model
            topmean = fminf(fmaxf(topmean, lo), hi);
            float hard   = (sAbove + topmean * (float)j) / (float)target;
            float n2mean = ws_f[ACC_OFF + layer] / Ns[layer];
            total += hard + n2mean;
        }
        __syncthreads();
    }
    if (tid == 0) out[0] = total;
}

extern "C" void kernel_launch(void* const* d_in, const int* in_sizes, int n_in,
                              void* d_out, int out_size, void* d_ws, size_t ws_size,
                              hipStream_t stream)
{
    const float* t0 = (const float*)d_in[0];
    const float* s0 = (const float*)d_in[1];
    const float* n0 = (const float*)d_in[2];
    const float* t1 = (const float*)d_in[3];
    const float* s1 = (const float*)d_in[4];
    const float* n1 = (const float*)d_in[5];
    const float* t2 = (const float*)d_in[6];
    const float* s2 = (const float*)d_in[7];
    const float* n2 = (const float*)d_in[8];

    // zero per-layer histograms + n^2 accumulators + tile counter (ws is NOT
    // re-poisoned between replays; memset is stream-ordered, graph-capturable)
    hipMemsetAsync(d_ws, 0, (size_t)(ACC_OFF + 8) * 4, stream);

    stfpm_hist<<<768, 256, 0, stream>>>(t0, s0, n0, t1, s1, n1, t2, s2, n2,
                                        (unsigned int*)d_ws, (float*)d_ws);
    stfpm_finalize<<<1, 256, 0, stream>>>((const unsigned int*)d_ws,
                                          (const float*)d_ws, (float*)d_out);
}

// Round 14
// 76.899 us; speedup vs baseline: 1.4287x; 1.4287x over previous
//
#include <hip/hip_runtime.h>

#define NBINS 2304                 // rebased: bin = (float_bits(d)>>18) - BINBASE
#define BINBASE 2048               // bin 0 <-> d ~ 5.4e-19; d<=4 -> bin <= 2113
#define ACC_OFF (3 * NBINS)        // word offset of per-layer n^2 accumulators in ws

typedef float    f4v __attribute__((ext_vector_type(4)));
typedef _Float16 h4v __attribute__((ext_vector_type(4)));

// ---- r11 tile body (measured best — byte-identical). Block = 16K elements
// (P positions x C channels) of one batch image; every thread 16 channels x 4
// consecutive positions; t,s,n loaded together (12 float4 in flight); t,s
// retained as f16; f32 norms reduce through LDS; register-only d histogram.
//
// Hard-won constraints (do not violate):
//  - DO NOT restructure the load loop (r5/r6: pipelines collapsed MLP/spilled).
//  - DO NOT split n into separate streaming blocks (r5, r12: −15%).
//  - DO NOT fuse finalize behind a ticket (r7: acq_rel = +140us cache-maint).
//  - DO NOT make blocks persistent / work-stealing (r13: −35%, defeats
//    hardware-pipelined block dispatch).
//  - launch_bounds waves-arg >= 4 flips the compiler into pressure-limited
//    scheduling and spills th/sh (r3/r5/r9/r10). KEEP (256,3); VGPR must
//    report 84 with zero scratch traffic.
template<int C, int HWSHIFT, int PSHIFT, int LAYER>
__device__ __forceinline__ void hist_layer(
    const float* __restrict__ t, const float* __restrict__ s, const float* __restrict__ n,
    int lb, unsigned int* __restrict__ ws_u, float* __restrict__ ws_f,
    unsigned int* cnt_sh, float* ov_sh, float* inv_sh)
{
    const int HW  = 1 << HWSHIFT;
    const int P   = 1 << PSHIFT;        // positions per block: 256/128/64
    const int NPQ = P >> 2;             // position-quads per wave: 64/32/16
    const int G   = 1024 >> PSHIFT;     // norm partials per position: 4/8/16
    const int tid = threadIdx.x;
    const int w   = tid >> 6;
    const int l   = tid & 63;
    const int pq  = l & (NPQ - 1);      // which position-quad
    const int cs  = l >> (PSHIFT - 2);  // channel sub-group within wave

    const int p0 = lb << PSHIFT;        // first flat position (never straddles b)
    const int b  = p0 >> HWSHIFT;
    const int q  = p0 & (HW - 1);
    const int c0 = w * (C / 4) + cs * 16;
    const size_t base = ((size_t)(b * C + c0) << HWSHIFT) + q + 4 * pq;

    const float* tp = t + base;
    const float* sp = s + base;
    const float* np = n + base;

    // ---- zero histogram up-front: hides under the in-flight global loads ----
    #pragma unroll
    for (int i = tid; i < NBINS / 4; i += 256)
        ((uint4*)cnt_sh)[i] = make_uint4(0u, 0u, 0u, 0u);

    // ---- pass 1: batched loads (12 float4 in flight), f32 norm accum, f16 retain ----
    h4v th[16], sh[16];
    f4v accT = {0.f,0.f,0.f,0.f}, accS = {0.f,0.f,0.f,0.f};
    float aN = 0.f;

    #pragma unroll
    for (int k0 = 0; k0 < 16; k0 += 4) {
        f4v tt[4], ss[4], nn[4];
        #pragma unroll
        for (int u = 0; u < 4; ++u) {
            const size_t o = (size_t)(k0 + u) << HWSHIFT;
            tt[u] = *(const f4v*)(tp + o);
            ss[u] = *(const f4v*)(sp + o);
            nn[u] = __builtin_nontemporal_load((const f4v*)(np + o));
        }
        #pragma unroll
        for (int u = 0; u < 4; ++u) {
            accT += tt[u] * tt[u];
            accS += ss[u] * ss[u];
            aN += nn[u].x*nn[u].x + nn[u].y*nn[u].y + nn[u].z*nn[u].z + nn[u].w*nn[u].w;
            th[k0+u] = (h4v){(_Float16)tt[u].x, (_Float16)tt[u].y,
                             (_Float16)tt[u].z, (_Float16)tt[u].w};
            sh[k0+u] = (h4v){(_Float16)ss[u].x, (_Float16)ss[u].y,
                             (_Float16)ss[u].z, (_Float16)ss[u].w};
        }
    }

    // cross-wave/lane-group norm combine via dedicated ov_sh buffer
    float* ovT = ov_sh;                 // [G][P] = 1024 floats
    float* ovS = ov_sh + 1024;          // 1024 floats
    float* ovN = ov_sh + 2048;          // 4 floats
    const int g = (w * (64 / NPQ)) + cs;        // partial group id, 0..G-1
    ((f4v*)ovT)[g * NPQ + pq] = accT;           // linearizes to ovT[g*P + pos]
    ((f4v*)ovS)[g * NPQ + pq] = accS;
    #pragma unroll
    for (int o = 32; o > 0; o >>= 1) aN += __shfl_down(aN, o, 64);
    if (l == 0) ovN[w] = aN;
    __syncthreads();

    if (tid < P) {
        float nT = 0.f, nS = 0.f;
        #pragma unroll
        for (int gg = 0; gg < G; ++gg) { nT += ovT[gg * P + tid]; nS += ovS[gg * P + tid]; }
        inv_sh[tid]     = 1.0f / fmaxf(sqrtf(nT), 1e-12f);
        inv_sh[P + tid] = 1.0f / fmaxf(sqrtf(nS), 1e-12f);
    }
    if (tid == 0)
        atomicAdd(&ws_f[ACC_OFF + LAYER], ovN[0] + ovN[1] + ovN[2] + ovN[3]);
    __syncthreads();

    // ---- pass 2 (registers only): d = (t*invT - s*invS)^2, count histogram ----
    __builtin_amdgcn_s_setprio(1);      // r8: neutral-to-slightly-positive, keep
    f4v iT = ((const f4v*)inv_sh)[pq];
    f4v iS = ((const f4v*)(inv_sh + P))[pq];
    #pragma unroll
    for (int k = 0; k < 16; ++k) {
        f4v tv = {(float)th[k].x, (float)th[k].y, (float)th[k].z, (float)th[k].w};
        f4v sv = {(float)sh[k].x, (float)sh[k].y, (float)sh[k].z, (float)sh[k].w};
        f4v a  = tv * iT - sv * iS;
        f4v d  = a * a;
        int b0 = min(max((int)(__float_as_uint(d.x) >> 18) - BINBASE, 0), NBINS - 1);
        int b1 = min(max((int)(__float_as_uint(d.y) >> 18) - BINBASE, 0), NBINS - 1);
        int b2 = min(max((int)(__float_as_uint(d.z) >> 18) - BINBASE, 0), NBINS - 1);
        int b3 = min(max((int)(__float_as_uint(d.w) >> 18) - BINBASE, 0), NBINS - 1);
        atomicAdd(&cnt_sh[b0], 1u);
        atomicAdd(&cnt_sh[b1], 1u);
        atomicAdd(&cnt_sh[b2], 1u);
        atomicAdd(&cnt_sh[b3], 1u);
    }
    __syncthreads();

    // ---- flush nonzero bins to global per-layer histogram ----
    unsigned int* gc = ws_u + LAYER * NBINS;
    #pragma unroll
    for (int i = tid; i < NBINS; i += 256) {
        unsigned c = cnt_sh[i];
        if (c) atomicAdd(&gc[i], c);
    }
    __builtin_amdgcn_s_setprio(0);
}

// Grid: 256 (layer2) + 512 (layer1) + 1024 (layer0) = 1792 = 7 * 256 uniform blocks.
__global__ __launch_bounds__(256, 3) void stfpm_hist(
    const float* __restrict__ t0, const float* __restrict__ s0, const float* __restrict__ n0,
    const float* __restrict__ t1, const float* __restrict__ s1, const float* __restrict__ n1,
    const float* __restrict__ t2, const float* __restrict__ s2, const float* __restrict__ n2,
    unsigned int* __restrict__ ws_u, float* __restrict__ ws_f)
{
    __shared__ __align__(16) unsigned int cnt_sh[NBINS];  // 9.2 KB
    __shared__ __align__(16) float ov_sh[2052];           // 8.2 KB norm overlay
    __shared__ __align__(16) float inv_sh[512];           // 2 KB
    const int bid = blockIdx.x;
    if (bid < 256)
        hist_layer<256, 10, 6, 2>(t2, s2, n2, bid,       ws_u, ws_f, cnt_sh, ov_sh, inv_sh);
    else if (bid < 768)
        hist_layer<128, 12, 7, 1>(t1, s1, n1, bid - 256, ws_u, ws_f, cnt_sh, ov_sh, inv_sh);
    else
        hist_layer<64,  14, 8, 0>(t0, s0, n0, bid - 768, ws_u, ws_f, cnt_sh, ov_sh, inv_sh);
}

__device__ __forceinline__ float bin_lo(int b) {
    return __uint_as_float((unsigned)(b + BINBASE) << 18);
}
__device__ __forceinline__ float bin_mid(int b) {
    return 0.5f * (bin_lo(b) + bin_lo(b + 1));
}

// 3 blocks, one per layer: scan counts from the top; full bins above the
// boundary contribute cnt * bin-midpoint; boundary bin uses the uniform-
// within-bin model. Each block atomicAdds (hard_mean + n2mean) into out[0]
// (zeroed by hipMemsetAsync before the hist launch). Float-atomic order across
// 3 blocks varies only last-ulp rounding — far below the absmax threshold.
__global__ __launch_bounds__(256) void stfpm_finalize(
    const unsigned int* __restrict__ ws_u, const float* __restrict__ ws_f,
    float* __restrict__ out)
{
    __shared__ unsigned int cchunk[256];
    __shared__ float        schunk[256];
    const int tid   = threadIdx.x;
    const int layer = blockIdx.x;

    const int   targets[3] = {16778, 8389, 4195};  // cnt = N-1-floor(0.999(N-1))
    const float Ns[3]      = {16777216.f, 8388608.f, 4194304.f};
    const int   CHUNK = NBINS / 256;  // 9

    const unsigned int* gc = ws_u + layer * NBINS;
    unsigned int c = 0; float sv = 0.f;
    const int b0 = tid * CHUNK;
    for (int i = 0; i < CHUNK; ++i) {
        unsigned cc = gc[b0 + i];
        c += cc;
        if (cc) sv += (float)cc * bin_mid(b0 + i);
    }
    cchunk[tid] = c; schunk[tid] = sv;
    __syncthreads();
    if (tid == 0) {
        const int target = targets[layer];
        long long cum = 0; float sAbove = 0.f;
        int ch = 255;
        while (ch >= 0 && cum + (long long)cchunk[ch] < target) {
            cum += cchunk[ch]; sAbove += schunk[ch]; --ch;
        }
        int bin = ch * CHUNK + CHUNK - 1;
        while (bin >= ch * CHUNK && cum + (long long)gc[bin] < target) {
            unsigned cc = gc[bin];
            cum += cc; sAbove += (float)cc * bin_mid(bin); --bin;
        }
        unsigned cb = gc[bin];          // boundary bin count (>=1)
        int j = target - (int)cum;      // elements taken from boundary bin
        float lo = bin_lo(bin), hi = bin_lo(bin + 1);
        float wd = hi - lo;
        float f  = (float)j / (float)cb;
        float topmean = hi - f * wd * 0.5f;  // mean of top-j under uniform model
        topmean = fminf(fmaxf(topmean, lo), hi);
        float hard   = (sAbove + topmean * (float)j) / (float)target;
        float n2mean = ws_f[ACC_OFF + layer] / Ns[layer];
        atomicAdd(out, hard + n2mean);
    }
}

extern "C" void kernel_launch(void* const* d_in, const int* in_sizes, int n_in,
                              void* d_out, int out_size, void* d_ws, size_t ws_size,
                              hipStream_t stream)
{
    const float* t0 = (const float*)d_in[0];
    const float* s0 = (const float*)d_in[1];
    const float* n0 = (const float*)d_in[2];
    const float* t1 = (const float*)d_in[3];
    const float* s1 = (const float*)d_in[4];
    const float* n1 = (const float*)d_in[5];
    const float* t2 = (const float*)d_in[6];
    const float* s2 = (const float*)d_in[7];
    const float* n2 = (const float*)d_in[8];

    // zero per-layer histograms + accumulators, and the scalar output
    // (ws/out are NOT re-poisoned between replays; both memsets are
    // stream-ordered and graph-capturable)
    hipMemsetAsync(d_ws, 0, (size_t)(ACC_OFF + 8) * 4, stream);
    hipMemsetAsync(d_out, 0, sizeof(float), stream);

    stfpm_hist<<<1792, 256, 0, stream>>>(t0, s0, n0, t1, s1, n1, t2, s2, n2,
                                         (unsigned int*)d_ws, (float*)d_ws);
    stfpm_finalize<<<3, 256, 0, stream>>>((const unsigned int*)d_ws,
                                          (const float*)d_ws, (float*)d_out);
}